// Round 6
// baseline (424.678 us; speedup 1.0000x reference)
//
#include <hip/hip_runtime.h>
#include <cstddef>
#include <cstdint>

#define DIM   256
#define KCODE 8192
#define NTOK  16384
#define NCBG  4          // phase1 code groups of 2048
#define HMARGIN 0.25f    // phase1 works in half-units (0.5*wn - dot)
#define UFLAG 0x40000000

typedef __attribute__((ext_vector_type(8))) short short8;
typedef __attribute__((ext_vector_type(8))) unsigned short ushort8;
typedef __attribute__((ext_vector_type(4))) unsigned short ushort4v;
typedef __attribute__((ext_vector_type(4))) float floatx4;

__device__ __forceinline__ unsigned short f2bf(float f) {  // RNE float->bf16
  uint32_t u = __builtin_bit_cast(uint32_t, f);
  return (unsigned short)((u + 0x7fffu + ((u >> 16) & 1u)) >> 16);
}
__device__ __forceinline__ float bf2f(unsigned short h) {
  return __builtin_bit_cast(float, (uint32_t)h << 16);
}

// ---- kernel 1: bf16 split convert (x negated, w two-word) + w norms ----
__global__ __launch_bounds__(256) void prep_kernel(const float* __restrict__ x,
    const float* __restrict__ w, unsigned short* __restrict__ x0n,
    unsigned short* __restrict__ w0, unsigned short* __restrict__ w1,
    float* __restrict__ wn2, float* __restrict__ wnf, int* __restrict__ ucount) {
  if (blockIdx.x == 0 && threadIdx.x == 0) *ucount = 0;
  const int lane = threadIdx.x & 63, wv = threadIdx.x >> 6;
  const int l32 = lane & 31;
  const int row = blockIdx.x * 8 + wv * 2 + (lane >> 5);
  const bool is_x = row < NTOK;
  const float* src = is_x ? (x + (size_t)row * DIM) : (w + (size_t)(row - NTOK) * DIM);
  const float4 f0 = ((const float4*)src)[l32 * 2];
  const float4 f1 = ((const float4*)src)[l32 * 2 + 1];
  const float f[8] = {f0.x, f0.y, f0.z, f0.w, f1.x, f1.y, f1.z, f1.w};
  if (is_x) {  // store bf16(-x): MFMA then accumulates (norm - dot) directly
    ushort8 o;
#pragma unroll
    for (int i = 0; i < 8; ++i) o[i] = f2bf(-f[i]);
    *(ushort8*)(x0n + (size_t)row * DIM + l32 * 8) = o;
  } else {     // two-word split: w = w0 + w1 (+ ~2^-17 residual)
    ushort8 h, l;
#pragma unroll
    for (int i = 0; i < 8; ++i) {
      h[i] = f2bf(f[i]);
      l[i] = f2bf(f[i] - bf2f(h[i]));
    }
    *(ushort8*)(w0 + (size_t)(row - NTOK) * DIM + l32 * 8) = h;
    *(ushort8*)(w1 + (size_t)(row - NTOK) * DIM + l32 * 8) = l;
    float s = f[0]*f[0] + f[1]*f[1] + f[2]*f[2] + f[3]*f[3] +
              f[4]*f[4] + f[5]*f[5] + f[6]*f[6] + f[7]*f[7];
#pragma unroll
    for (int off = 1; off < 32; off <<= 1) s += __shfl_xor(s, off);
    if (l32 == 0) { wn2[row - NTOK] = 0.5f * s; wnf[row - NTOK] = s; }
  }
}

// ---- kernel 2: phase1 bf16 screen. Wave tile 32 tok x 32 codes (low VGPR). ----
// block = 64 tok x 2048 codes; 1024 blocks (4/CU); af[2][8]=64 VGPR -> no spills
__global__ __launch_bounds__(256) __attribute__((amdgpu_waves_per_eu(3, 4)))
void phase1_kernel(
    const unsigned short* __restrict__ x0n, const unsigned short* __restrict__ w0,
    const float* __restrict__ wn2,
    float* __restrict__ pv1, int* __restrict__ pc1, float* __restrict__ pv2) {
  __shared__ float red[6144];  // 24 KB: rv1[2048] rv2[2048] rc1[2048]
  const int tid = threadIdx.x;
  const int tb = blockIdx.x >> 2;    // 0..255
  const int cbg = blockIdx.x & 3;    // XCD&3 -> one 1MB w0 slice per XCD L2
  const int lane = tid & 63, wv = tid >> 6;
  const int wm = wv & 1, wnb = wv >> 1;
  const int l15 = lane & 15, quad = lane >> 4;

  short8 af[2][8];  // resident A fragments (negated-x bf16): 64 VGPRs
#pragma unroll
  for (int mt = 0; mt < 2; ++mt) {
    const unsigned short* xr =
        x0n + (size_t)(tb * 64 + wm * 32 + mt * 16 + l15) * DIM + quad * 8;
#pragma unroll
    for (int kc = 0; kc < 8; ++kc) af[mt][kc] = *(const short8*)(xr + kc * 32);
  }

  float bv1[8], bv2[8];
  int bc1[8];
#pragma unroll
  for (int i = 0; i < 8; ++i) { bv1[i] = -3.4e38f; bv2[i] = -3.4e38f; bc1[i] = 0; }

  const unsigned short* wp = w0 + (size_t)(cbg * 2048 + wnb * 32 + l15) * DIM + quad * 8;
  const float* wnp = wn2 + cbg * 2048 + wnb * 32 + l15;
  int code0 = cbg * 2048 + wnb * 32 + l15;
  float nw0 = wnp[0], nw1 = wnp[16];

#pragma unroll 1
  for (int sub = 0; sub < 32; ++sub) {
    const float cw0 = nw0, cw1 = nw1;
    wnp += 64;
    if (sub < 31) { nw0 = wnp[0]; nw1 = wnp[16]; }  // prefetch next sub's norms
    floatx4 acc[2][2];
#pragma unroll
    for (int mt = 0; mt < 2; ++mt) {
      acc[mt][0] = (floatx4){cw0, cw0, cw0, cw0};
      acc[mt][1] = (floatx4){cw1, cw1, cw1, cw1};
    }
#pragma unroll
    for (int kc = 0; kc < 8; ++kc) {
      const short8 b0 = *(const short8*)(wp + kc * 32);
      const short8 b1 = *(const short8*)(wp + 16 * DIM + kc * 32);
#pragma unroll
      for (int mt = 0; mt < 2; ++mt) {
        acc[mt][0] = __builtin_amdgcn_mfma_f32_16x16x32_bf16(af[mt][kc], b0, acc[mt][0], 0, 0, 0);
        acc[mt][1] = __builtin_amdgcn_mfma_f32_16x16x32_bf16(af[mt][kc], b1, acc[mt][1], 0, 0, 0);
      }
    }
    // acc = wn/2 - dot. Pair-merge 2 candidates/cell into running top-2 (R5-proven).
#pragma unroll
    for (int mt = 0; mt < 2; ++mt) {
#pragma unroll
      for (int reg = 0; reg < 4; ++reg) {
        const int cell = mt * 4 + reg;
        const float c0 = acc[mt][0][reg], c1 = acc[mt][1][reg];
        const float hi = fmaxf(c0, c1), lo = fminf(c0, c1);
        const int ch = (c1 > c0) ? (code0 + 16) : code0;  // tie -> lower code
        const float t = fminf(bv1[cell], hi);
        bc1[cell] = (hi > bv1[cell]) ? ch : bc1[cell];    // tie -> earlier (lower)
        bv1[cell] = fmaxf(bv1[cell], hi);
        bv2[cell] = fmaxf(fmaxf(bv2[cell], t), lo);       // v_max3_f32
      }
    }
    wp += (size_t)64 * DIM;
    code0 += 64;
  }

  // single per-block epilogue: cross-column reduce via LDS
  float* rv1 = red;
  float* rv2 = red + 2048;
  int* rc1 = (int*)(red + 4096);
  const int cg = wnb * 16 + l15;
#pragma unroll
  for (int mt = 0; mt < 2; ++mt)
#pragma unroll
    for (int reg = 0; reg < 4; ++reg) {
      const int tok = wm * 32 + mt * 16 + quad * 4 + reg;  // C/D: row=quad*4+reg
      rv1[tok * 32 + cg] = bv1[mt * 4 + reg];
      rv2[tok * 32 + cg] = bv2[mt * 4 + reg];
      rc1[tok * 32 + cg] = bc1[mt * 4 + reg];
    }
  __syncthreads();
  if (tid < 64) {
    float V1 = rv1[tid * 32], V2 = rv2[tid * 32];
    int C1 = rc1[tid * 32];
#pragma unroll 4
    for (int j = 1; j < 32; ++j) {
      const float v1 = rv1[tid * 32 + j], v2 = rv2[tid * 32 + j];
      const int c1 = rc1[tid * 32 + j];
      if (v1 > V1) { V2 = fmaxf(V1, v2); V1 = v1; C1 = c1; }
      else V2 = fmaxf(V2, v1);   // exact tie -> gap 0 -> uncertain -> rescore
    }
    const size_t o = (size_t)cbg * NTOK + tb * 64 + tid;
    pv1[o] = V1; pc1[o] = C1; pv2[o] = V2;
  }
}

// ---- kernel 3: merge 4 code-group partials; flagged final_idx + uncertain list ----
__global__ __launch_bounds__(256) void reduce_kernel(
    const float* __restrict__ pv1, const int* __restrict__ pc1,
    const float* __restrict__ pv2, int* __restrict__ final_idx,
    int* __restrict__ ucount, int* __restrict__ ulist) {
  const int n = blockIdx.x * 256 + threadIdx.x;
  float V1 = -3.4e38f, V2 = -3.4e38f;
  int C1 = 0;
#pragma unroll
  for (int cb = 0; cb < NCBG; ++cb) {
    const size_t o = (size_t)cb * NTOK + n;
    const float v1 = pv1[o], v2 = pv2[o];
    const int c1 = pc1[o];
    if (v1 > V1) { V2 = fmaxf(V1, v2); V1 = v1; C1 = c1; }
    else V2 = fmaxf(V2, v1);
  }
  if (V1 - V2 < HMARGIN) {
    const int p = atomicAdd(ucount, 1);
    ulist[p] = n;
    final_idx[n] = UFLAG | p;   // gather resolves via p2 slot p
  } else {
    final_idx[n] = C1;
  }
}

// ---- kernel 4: gather uncertain tokens into compact two-word bf16 rows ----
__global__ __launch_bounds__(256) void xgather_kernel(const float* __restrict__ x,
    const unsigned short* __restrict__ x0n, const int* __restrict__ ucount,
    const int* __restrict__ ulist, unsigned short* __restrict__ xgh,
    unsigned short* __restrict__ xgl) {
  const int uc = *ucount;
  const int ucp = (uc + 63) & ~63;
  const int wgid = blockIdx.x * 4 + (threadIdx.x >> 6);
  const int lane = threadIdx.x & 63;
  for (int s = wgid; s < ucp; s += 1024) {
    ushort4v h = (ushort4v){0, 0, 0, 0}, l = (ushort4v){0, 0, 0, 0};
    if (s < uc) {
      const int tok = ulist[s];
      h = ((const ushort4v*)(x0n + (size_t)tok * DIM))[lane];
      const float4 f = ((const float4*)(x + (size_t)tok * DIM))[lane];
      l[0] = f2bf(-f.x - bf2f(h[0]));
      l[1] = f2bf(-f.y - bf2f(h[1]));
      l[2] = f2bf(-f.z - bf2f(h[2]));
      l[3] = f2bf(-f.w - bf2f(h[3]));
    }
    ((ushort4v*)(xgh + (size_t)s * DIM))[lane] = h;
    ((ushort4v*)(xgl + (size_t)s * DIM))[lane] = l;
  }
}

// ---- kernel 5: exact-ish rescore via 2-word bf16 split MFMA (4 products) ----
// block = 64 slots x 256-code slice; grid 2048 = 64 g-slots x 32 slices
__global__ __launch_bounds__(256) __attribute__((amdgpu_waves_per_eu(2, 4)))
void rescore_kernel(
    const unsigned short* __restrict__ xgh, const unsigned short* __restrict__ xgl,
    const unsigned short* __restrict__ w0, const unsigned short* __restrict__ w1,
    const float* __restrict__ wnf, const int* __restrict__ ucount,
    float* __restrict__ p2v, int* __restrict__ p2c) {
  const int uc = *ucount;
  if (uc == 0) return;
  const int ucp = (uc + 63) & ~63;
  const int sl = blockIdx.x & 31, g0 = blockIdx.x >> 5;
  __shared__ float red2[4096];  // 16 KB: rv[2048] rc[2048]
  const int tid = threadIdx.x;
  const int lane = tid & 63, wv = tid >> 6;
  const int wm = wv & 1, wnb = wv >> 1;
  const int l15 = lane & 15, quad = lane >> 4;

  for (int g = g0; g * 64 < ucp; g += 64) {
    short8 ah[2][8], al[2][8];  // 128 VGPRs
#pragma unroll
    for (int mt = 0; mt < 2; ++mt) {
      const size_t rb = (size_t)(g * 64 + wm * 32 + mt * 16 + l15) * DIM + quad * 8;
#pragma unroll
      for (int kc = 0; kc < 8; ++kc) {
        ah[mt][kc] = *(const short8*)(xgh + rb + kc * 32);
        al[mt][kc] = *(const short8*)(xgl + rb + kc * 32);
      }
    }
    float bv[8];
    int bc[8];
#pragma unroll
    for (int i = 0; i < 8; ++i) { bv[i] = -3.4e38f; bc[i] = 0; }

    const unsigned short* wph = w0 + (size_t)(sl * 256 + wnb * 32 + l15) * DIM + quad * 8;
    const unsigned short* wpl = w1 + (size_t)(sl * 256 + wnb * 32 + l15) * DIM + quad * 8;
    const float* wnp = wnf + sl * 256 + wnb * 32 + l15;
    int code0 = sl * 256 + wnb * 32 + l15;

#pragma unroll 1
    for (int sub = 0; sub < 4; ++sub) {
      floatx4 acc[2][2];
#pragma unroll
      for (int mt = 0; mt < 2; ++mt)
#pragma unroll
        for (int nt = 0; nt < 2; ++nt) acc[mt][nt] = (floatx4){0.f, 0.f, 0.f, 0.f};
#pragma unroll
      for (int kc = 0; kc < 8; ++kc) {
        const short8 bh0 = *(const short8*)(wph + kc * 32);
        const short8 bh1 = *(const short8*)(wph + 16 * DIM + kc * 32);
        const short8 bl0 = *(const short8*)(wpl + kc * 32);
        const short8 bl1 = *(const short8*)(wpl + 16 * DIM + kc * 32);
#pragma unroll
        for (int mt = 0; mt < 2; ++mt) {
          acc[mt][0] = __builtin_amdgcn_mfma_f32_16x16x32_bf16(al[mt][kc], bl0, acc[mt][0], 0, 0, 0);
          acc[mt][0] = __builtin_amdgcn_mfma_f32_16x16x32_bf16(ah[mt][kc], bl0, acc[mt][0], 0, 0, 0);
          acc[mt][0] = __builtin_amdgcn_mfma_f32_16x16x32_bf16(al[mt][kc], bh0, acc[mt][0], 0, 0, 0);
          acc[mt][0] = __builtin_amdgcn_mfma_f32_16x16x32_bf16(ah[mt][kc], bh0, acc[mt][0], 0, 0, 0);
          acc[mt][1] = __builtin_amdgcn_mfma_f32_16x16x32_bf16(al[mt][kc], bl1, acc[mt][1], 0, 0, 0);
          acc[mt][1] = __builtin_amdgcn_mfma_f32_16x16x32_bf16(ah[mt][kc], bl1, acc[mt][1], 0, 0, 0);
          acc[mt][1] = __builtin_amdgcn_mfma_f32_16x16x32_bf16(al[mt][kc], bh1, acc[mt][1], 0, 0, 0);
          acc[mt][1] = __builtin_amdgcn_mfma_f32_16x16x32_bf16(ah[mt][kc], bh1, acc[mt][1], 0, 0, 0);
        }
      }
      const float wn0 = wnp[0], wn1 = wnp[16];
      // acc = -(x.w); dist = wn + 2*acc
#pragma unroll
      for (int mt = 0; mt < 2; ++mt) {
#pragma unroll
        for (int reg = 0; reg < 4; ++reg) {
          const int cell = mt * 4 + reg;
          const float d0 = fmaf(2.0f, acc[mt][0][reg], wn0);
          const float d1 = fmaf(2.0f, acc[mt][1][reg], wn1);
          const float hi = fmaxf(d0, d1);
          const int ch = (d1 > d0) ? (code0 + 16) : code0;  // tie -> lower code
          bc[cell] = (hi > bv[cell]) ? ch : bc[cell];
          bv[cell] = fmaxf(bv[cell], hi);
        }
      }
      wph += (size_t)64 * DIM;
      wpl += (size_t)64 * DIM;
      wnp += 64;
      code0 += 64;
    }

    // epilogue: cross-column reduce for this g-group
    float* rv = red2;
    int* rc = (int*)(red2 + 2048);
    __syncthreads();  // protect red2 reuse across g iterations
    const int cg = wnb * 16 + l15;
#pragma unroll
    for (int mt = 0; mt < 2; ++mt)
#pragma unroll
      for (int reg = 0; reg < 4; ++reg) {
        const int tok = wm * 32 + mt * 16 + quad * 4 + reg;
        rv[tok * 32 + cg] = bv[mt * 4 + reg];
        rc[tok * 32 + cg] = bc[mt * 4 + reg];
      }
    __syncthreads();
    if (tid < 64) {
      const int s = g * 64 + tid;
      if (s < uc) {
        float V = rv[tid * 32];
        int C = rc[tid * 32];
#pragma unroll 4
        for (int j = 1; j < 32; ++j) {
          const float v = rv[tid * 32 + j];
          const int c = rc[tid * 32 + j];
          if (v > V || (v == V && c < C)) { V = v; C = c; }
        }
        p2v[(size_t)sl * NTOK + s] = V;
        p2c[(size_t)sl * NTOK + s] = C;
      }
    }
  }
}

// ---- kernel 6: fused slice-merge + gather ----
__global__ __launch_bounds__(256) void gather_kernel(const float* __restrict__ w,
    const int* __restrict__ final_idx, const float* __restrict__ p2v,
    const int* __restrict__ p2c, float* __restrict__ out) {
  const int lane = threadIdx.x & 63;
  const int n = blockIdx.x * 4 + (threadIdx.x >> 6);
  int f = final_idx[n];
  if (f & UFLAG) {
    const int s = f & 0x3FFF;
    const int sl = lane & 31;
    float v = p2v[(size_t)sl * NTOK + s];
    int c = p2c[(size_t)sl * NTOK + s];
#pragma unroll
    for (int off = 1; off < 32; off <<= 1) {
      const float ov = __shfl_xor(v, off);
      const int oc = __shfl_xor(c, off);
      if (ov > v || (ov == v && oc < c)) { v = ov; c = oc; }
    }
    f = c;  // uniform across each 32-lane half (both halves identical)
  }
  ((float4*)(out + (size_t)n * DIM))[lane] = ((const float4*)(w + (size_t)f * DIM))[lane];
}

extern "C" void kernel_launch(void* const* d_in, const int* in_sizes, int n_in,
                              void* d_out, int out_size, void* d_ws, size_t ws_size,
                              hipStream_t stream) {
  const float* x = (const float*)d_in[0];
  const float* w = (const float*)d_in[1];
  float* out = (float*)d_out;

  char* ws = (char*)d_ws;   // ~38.7 MB used
  unsigned short* x0n = (unsigned short*)(ws);             // 8388608
  unsigned short* w0 = (unsigned short*)(ws + 8388608);    // 4194304
  unsigned short* w1 = (unsigned short*)(ws + 12582912);   // 4194304
  float* wn2 = (float*)(ws + 16777216);                    // 32768
  float* wnf = (float*)(ws + 16809984);                    // 32768
  float* pv1 = (float*)(ws + 16842752);                    // 262144
  int*   pc1 = (int*)  (ws + 17104896);                    // 262144
  float* pv2 = (float*)(ws + 17367040);                    // 262144
  int* final_idx = (int*)(ws + 17629184);                  // 65536
  int* ucount = (int*)(ws + 17694720);                     // 256
  int* ulist  = (int*)(ws + 17694976);                     // 65536
  unsigned short* xgh = (unsigned short*)(ws + 17760512);  // 8388608
  unsigned short* xgl = (unsigned short*)(ws + 26149120);  // 8388608
  float* p2v = (float*)(ws + 34537728);                    // 2097152
  int*   p2c = (int*)  (ws + 36634880);                    // 2097152

  prep_kernel<<<3072, 256, 0, stream>>>(x, w, x0n, w0, w1, wn2, wnf, ucount);
  phase1_kernel<<<256 * NCBG, 256, 0, stream>>>(x0n, w0, wn2, pv1, pc1, pv2);
  reduce_kernel<<<NTOK / 256, 256, 0, stream>>>(pv1, pc1, pv2, final_idx, ucount, ulist);
  xgather_kernel<<<256, 256, 0, stream>>>(x, x0n, ucount, ulist, xgh, xgl);
  rescore_kernel<<<64 * 32, 256, 0, stream>>>(xgh, xgl, w0, w1, wnf, ucount, p2v, p2c);
  gather_kernel<<<NTOK / 4, 256, 0, stream>>>(w, final_idx, p2v, p2c, out);
}

// Round 8
// 242.279 us; speedup vs baseline: 1.7528x; 1.7528x over previous
//
#include <hip/hip_runtime.h>
#include <cstddef>
#include <cstdint>

#define DIM   256
#define KCODE 8192
#define NTOK  16384
#define NCBG  8          // phase1 code groups of 1024
#define HMARGIN 0.25f    // phase1 works in half-units (0.5*wn - dot)
#define UFLAG 0x40000000
#define BSTRIDE 264      // LDS B row stride in shorts (256 + 8 pad)

typedef __attribute__((ext_vector_type(8))) short short8;
typedef __attribute__((ext_vector_type(8))) unsigned short ushort8;
typedef __attribute__((ext_vector_type(4))) unsigned short ushort4v;
typedef __attribute__((ext_vector_type(4))) float floatx4;

__device__ __forceinline__ unsigned short f2bf(float f) {  // RNE float->bf16
  uint32_t u = __builtin_bit_cast(uint32_t, f);
  return (unsigned short)((u + 0x7fffu + ((u >> 16) & 1u)) >> 16);
}
__device__ __forceinline__ float bf2f(unsigned short h) {
  return __builtin_bit_cast(float, (uint32_t)h << 16);
}

// ---- kernel 1: bf16 split convert (x negated, w two-word) + w norms ----
__global__ __launch_bounds__(256) void prep_kernel(const float* __restrict__ x,
    const float* __restrict__ w, unsigned short* __restrict__ x0n,
    unsigned short* __restrict__ w0, unsigned short* __restrict__ w1,
    float* __restrict__ wn2, float* __restrict__ wnf, int* __restrict__ ucount) {
  if (blockIdx.x == 0 && threadIdx.x == 0) *ucount = 0;
  const int lane = threadIdx.x & 63, wv = threadIdx.x >> 6;
  const int l32 = lane & 31;
  const int row = blockIdx.x * 8 + wv * 2 + (lane >> 5);
  const bool is_x = row < NTOK;
  const float* src = is_x ? (x + (size_t)row * DIM) : (w + (size_t)(row - NTOK) * DIM);
  const float4 f0 = ((const float4*)src)[l32 * 2];
  const float4 f1 = ((const float4*)src)[l32 * 2 + 1];
  const float f[8] = {f0.x, f0.y, f0.z, f0.w, f1.x, f1.y, f1.z, f1.w};
  if (is_x) {  // store bf16(-x): MFMA then accumulates (norm - dot) directly
    ushort8 o;
#pragma unroll
    for (int i = 0; i < 8; ++i) o[i] = f2bf(-f[i]);
    *(ushort8*)(x0n + (size_t)row * DIM + l32 * 8) = o;
  } else {     // two-word split: w = w0 + w1 (+ ~2^-17 residual)
    ushort8 h, l;
#pragma unroll
    for (int i = 0; i < 8; ++i) {
      h[i] = f2bf(f[i]);
      l[i] = f2bf(f[i] - bf2f(h[i]));
    }
    *(ushort8*)(w0 + (size_t)(row - NTOK) * DIM + l32 * 8) = h;
    *(ushort8*)(w1 + (size_t)(row - NTOK) * DIM + l32 * 8) = l;
    float s = f[0]*f[0] + f[1]*f[1] + f[2]*f[2] + f[3]*f[3] +
              f[4]*f[4] + f[5]*f[5] + f[6]*f[6] + f[7]*f[7];
#pragma unroll
    for (int off = 1; off < 32; off <<= 1) s += __shfl_xor(s, off);
    if (l32 == 0) { wn2[row - NTOK] = 0.5f * s; wnf[row - NTOK] = s; }
  }
}

// ---- kernel 2: phase1 bf16 screen. A in VGPRs (64 tok/wave); B LDS-shared. ----
// block = 256 tok x 1024 codes; grid 512 (2/CU). Per 32-code sub: 16KB B tile
// staged by all 256 threads (4x int4 each — full coverage), register-prefetched
// one sub ahead. Per wave per sub: 16 ds_read_b128 -> 64 MFMAs (1:4 ratio).
__global__ __launch_bounds__(256) __attribute__((amdgpu_waves_per_eu(2, 2)))
void phase1_kernel(
    const unsigned short* __restrict__ x0n, const unsigned short* __restrict__ w0,
    const float* __restrict__ wn2,
    float* __restrict__ pv1, int* __restrict__ pc1, float* __restrict__ pv2) {
  __shared__ char smem[49152];  // B tile 32*264*2=16896 B; epilogue 48KB aliases
  unsigned short* Bs = (unsigned short*)smem;
  const int tid = threadIdx.x;
  const int tb = blockIdx.x >> 3;    // 0..63 (256 tokens)
  const int cbg = blockIdx.x & 7;    // blockIdx%8 = XCD -> 512KB w0 slice per XCD L2
  const int lane = tid & 63, wv = tid >> 6;
  const int l15 = lane & 15, quad = lane >> 4;

  // resident A: wave wv owns 64 tokens; af[4][8] = 128 VGPRs
  short8 af[4][8];
#pragma unroll
  for (int mt = 0; mt < 4; ++mt) {
    const unsigned short* xr =
        x0n + (size_t)(tb * 256 + wv * 64 + mt * 16 + l15) * DIM + quad * 8;
#pragma unroll
    for (int kc = 0; kc < 8; ++kc) af[mt][kc] = *(const short8*)(xr + kc * 32);
  }

  float bv1[16], bv2[16];
  int bc1[16];
#pragma unroll
  for (int i = 0; i < 16; ++i) { bv1[i] = -3.4e38f; bv2[i] = -3.4e38f; bc1[i] = 0; }

  // staging: k-th instr: row = (tid>>5) + k*8 (0..31 over k=0..3), col = (tid&31)*16B
  const int s_row = tid >> 5;
  const int s_col = (tid & 31) * 8;  // shorts
  const unsigned short* gsrc = w0 + (size_t)(cbg * 1024 + s_row) * DIM + s_col;
  unsigned short* ldst = Bs + s_row * BSTRIDE + s_col;

  int4 st[4];
#pragma unroll
  for (int k = 0; k < 4; ++k) st[k] = *(const int4*)(gsrc + k * 2048);  // sub 0
  const float* wnp = wn2 + cbg * 1024 + l15;
  float nw0 = wnp[0], nw1 = wnp[16];
  int code0 = cbg * 1024 + l15;

#pragma unroll 1
  for (int sub = 0; sub < 32; ++sub) {
    __syncthreads();   // previous sub's ds_reads complete
#pragma unroll
    for (int k = 0; k < 4; ++k) *(int4*)(ldst + k * 8 * BSTRIDE) = st[k];
    __syncthreads();   // tile visible
    if (sub < 31) {    // prefetch sub+1 (32 rows = 8192 shorts ahead)
      const unsigned short* gn = gsrc + (size_t)(sub + 1) * 8192;
#pragma unroll
      for (int k = 0; k < 4; ++k) st[k] = *(const int4*)(gn + k * 2048);
    }
    const float cw0 = nw0, cw1 = nw1;
    wnp += 32;
    if (sub < 31) { nw0 = wnp[0]; nw1 = wnp[16]; }
    floatx4 acc[4][2];
#pragma unroll
    for (int mt = 0; mt < 4; ++mt) {
      acc[mt][0] = (floatx4){cw0, cw0, cw0, cw0};
      acc[mt][1] = (floatx4){cw1, cw1, cw1, cw1};
    }
#pragma unroll
    for (int kc = 0; kc < 8; ++kc) {
      const short8 b0 = *(const short8*)(Bs + l15 * BSTRIDE + kc * 32 + quad * 8);
      const short8 b1 = *(const short8*)(Bs + (16 + l15) * BSTRIDE + kc * 32 + quad * 8);
#pragma unroll
      for (int mt = 0; mt < 4; ++mt) {
        acc[mt][0] = __builtin_amdgcn_mfma_f32_16x16x32_bf16(af[mt][kc], b0, acc[mt][0], 0, 0, 0);
        acc[mt][1] = __builtin_amdgcn_mfma_f32_16x16x32_bf16(af[mt][kc], b1, acc[mt][1], 0, 0, 0);
      }
    }
    // acc = wn/2 - dot. Pair-merge 2 candidates/cell into running top-2 (R5-proven).
#pragma unroll
    for (int mt = 0; mt < 4; ++mt) {
#pragma unroll
      for (int reg = 0; reg < 4; ++reg) {
        const int cell = mt * 4 + reg;
        const float c0 = acc[mt][0][reg], c1 = acc[mt][1][reg];
        const float hi = fmaxf(c0, c1), lo = fminf(c0, c1);
        const int ch = (c1 > c0) ? (code0 + 16) : code0;  // tie -> lower code
        const float t = fminf(bv1[cell], hi);
        bc1[cell] = (hi > bv1[cell]) ? ch : bc1[cell];    // tie -> earlier (lower)
        bv1[cell] = fmaxf(bv1[cell], hi);
        bv2[cell] = fmaxf(fmaxf(bv2[cell], t), lo);       // v_max3_f32
      }
    }
    code0 += 32;
  }

  // single per-block epilogue: 16 column-streams per token, reduce via LDS
  __syncthreads();
  float* rv1 = (float*)smem;             // [256][16] = 16 KB
  float* rv2 = (float*)(smem + 16384);
  int*   rc1 = (int*)(smem + 32768);
#pragma unroll
  for (int mt = 0; mt < 4; ++mt)
#pragma unroll
    for (int reg = 0; reg < 4; ++reg) {
      const int tok = wv * 64 + mt * 16 + quad * 4 + reg;  // C/D: row=quad*4+reg
      rv1[tok * 16 + l15] = bv1[mt * 4 + reg];
      rv2[tok * 16 + l15] = bv2[mt * 4 + reg];
      rc1[tok * 16 + l15] = bc1[mt * 4 + reg];
    }
  __syncthreads();
  {
    float V1 = rv1[tid * 16], V2 = rv2[tid * 16];
    int C1 = rc1[tid * 16];
#pragma unroll 4
    for (int j = 1; j < 16; ++j) {
      const float v1 = rv1[tid * 16 + j], v2 = rv2[tid * 16 + j];
      const int c1 = rc1[tid * 16 + j];
      if (v1 > V1) { V2 = fmaxf(V1, v2); V1 = v1; C1 = c1; }
      else V2 = fmaxf(V2, v1);   // exact tie -> gap 0 -> uncertain -> rescore
    }
    const size_t o = (size_t)cbg * NTOK + tb * 256 + tid;
    pv1[o] = V1; pc1[o] = C1; pv2[o] = V2;
  }
}

// ---- kernel 3: merge 8 code-group partials; flagged final_idx + uncertain list ----
__global__ __launch_bounds__(256) void reduce_kernel(
    const float* __restrict__ pv1, const int* __restrict__ pc1,
    const float* __restrict__ pv2, int* __restrict__ final_idx,
    int* __restrict__ ucount, int* __restrict__ ulist) {
  const int n = blockIdx.x * 256 + threadIdx.x;
  float V1 = -3.4e38f, V2 = -3.4e38f;
  int C1 = 0;
#pragma unroll
  for (int cb = 0; cb < NCBG; ++cb) {
    const size_t o = (size_t)cb * NTOK + n;
    const float v1 = pv1[o], v2 = pv2[o];
    const int c1 = pc1[o];
    if (v1 > V1) { V2 = fmaxf(V1, v2); V1 = v1; C1 = c1; }
    else V2 = fmaxf(V2, v1);
  }
  if (V1 - V2 < HMARGIN) {
    const int p = atomicAdd(ucount, 1);
    ulist[p] = n;
    final_idx[n] = UFLAG | p;   // gather resolves via p2 slot p
  } else {
    final_idx[n] = C1;
  }
}

// ---- kernel 4: gather uncertain tokens into compact two-word bf16 rows ----
__global__ __launch_bounds__(256) void xgather_kernel(const float* __restrict__ x,
    const unsigned short* __restrict__ x0n, const int* __restrict__ ucount,
    const int* __restrict__ ulist, unsigned short* __restrict__ xgh,
    unsigned short* __restrict__ xgl) {
  const int uc = *ucount;
  const int ucp = (uc + 63) & ~63;
  const int wgid = blockIdx.x * 4 + (threadIdx.x >> 6);
  const int lane = threadIdx.x & 63;
  for (int s = wgid; s < ucp; s += 1024) {
    ushort4v h = (ushort4v){0, 0, 0, 0}, l = (ushort4v){0, 0, 0, 0};
    if (s < uc) {
      const int tok = ulist[s];
      h = ((const ushort4v*)(x0n + (size_t)tok * DIM))[lane];
      const float4 f = ((const float4*)(x + (size_t)tok * DIM))[lane];
      l[0] = f2bf(-f.x - bf2f(h[0]));
      l[1] = f2bf(-f.y - bf2f(h[1]));
      l[2] = f2bf(-f.z - bf2f(h[2]));
      l[3] = f2bf(-f.w - bf2f(h[3]));
    }
    ((ushort4v*)(xgh + (size_t)s * DIM))[lane] = h;
    ((ushort4v*)(xgl + (size_t)s * DIM))[lane] = l;
  }
}

// ---- kernel 5: exact-ish rescore via 2-word bf16 split MFMA (4 products) ----
// block = 64 slots x 256-code slice; grid 2048 = 64 g-slots x 32 slices
__global__ __launch_bounds__(256) __attribute__((amdgpu_waves_per_eu(2, 4)))
void rescore_kernel(
    const unsigned short* __restrict__ xgh, const unsigned short* __restrict__ xgl,
    const unsigned short* __restrict__ w0, const unsigned short* __restrict__ w1,
    const float* __restrict__ wnf, const int* __restrict__ ucount,
    float* __restrict__ p2v, int* __restrict__ p2c) {
  const int uc = *ucount;
  if (uc == 0) return;
  const int ucp = (uc + 63) & ~63;
  const int sl = blockIdx.x & 31, g0 = blockIdx.x >> 5;
  __shared__ float red2[4096];  // 16 KB: rv[2048] rc[2048]
  const int tid = threadIdx.x;
  const int lane = tid & 63, wv = tid >> 6;
  const int wm = wv & 1, wnb = wv >> 1;
  const int l15 = lane & 15, quad = lane >> 4;

  for (int g = g0; g * 64 < ucp; g += 64) {
    short8 ah[2][8], al[2][8];  // 128 VGPRs
#pragma unroll
    for (int mt = 0; mt < 2; ++mt) {
      const size_t rb = (size_t)(g * 64 + wm * 32 + mt * 16 + l15) * DIM + quad * 8;
#pragma unroll
      for (int kc = 0; kc < 8; ++kc) {
        ah[mt][kc] = *(const short8*)(xgh + rb + kc * 32);
        al[mt][kc] = *(const short8*)(xgl + rb + kc * 32);
      }
    }
    float bv[8];
    int bc[8];
#pragma unroll
    for (int i = 0; i < 8; ++i) { bv[i] = -3.4e38f; bc[i] = 0; }

    const unsigned short* wph = w0 + (size_t)(sl * 256 + wnb * 32 + l15) * DIM + quad * 8;
    const unsigned short* wpl = w1 + (size_t)(sl * 256 + wnb * 32 + l15) * DIM + quad * 8;
    const float* wnp = wnf + sl * 256 + wnb * 32 + l15;
    int code0 = sl * 256 + wnb * 32 + l15;

#pragma unroll 1
    for (int sub = 0; sub < 4; ++sub) {
      floatx4 acc[2][2];
#pragma unroll
      for (int mt = 0; mt < 2; ++mt)
#pragma unroll
        for (int nt = 0; nt < 2; ++nt) acc[mt][nt] = (floatx4){0.f, 0.f, 0.f, 0.f};
#pragma unroll
      for (int kc = 0; kc < 8; ++kc) {
        const short8 bh0 = *(const short8*)(wph + kc * 32);
        const short8 bh1 = *(const short8*)(wph + 16 * DIM + kc * 32);
        const short8 bl0 = *(const short8*)(wpl + kc * 32);
        const short8 bl1 = *(const short8*)(wpl + 16 * DIM + kc * 32);
#pragma unroll
        for (int mt = 0; mt < 2; ++mt) {
          acc[mt][0] = __builtin_amdgcn_mfma_f32_16x16x32_bf16(al[mt][kc], bl0, acc[mt][0], 0, 0, 0);
          acc[mt][0] = __builtin_amdgcn_mfma_f32_16x16x32_bf16(ah[mt][kc], bl0, acc[mt][0], 0, 0, 0);
          acc[mt][0] = __builtin_amdgcn_mfma_f32_16x16x32_bf16(al[mt][kc], bh0, acc[mt][0], 0, 0, 0);
          acc[mt][0] = __builtin_amdgcn_mfma_f32_16x16x32_bf16(ah[mt][kc], bh0, acc[mt][0], 0, 0, 0);
          acc[mt][1] = __builtin_amdgcn_mfma_f32_16x16x32_bf16(al[mt][kc], bl1, acc[mt][1], 0, 0, 0);
          acc[mt][1] = __builtin_amdgcn_mfma_f32_16x16x32_bf16(ah[mt][kc], bl1, acc[mt][1], 0, 0, 0);
          acc[mt][1] = __builtin_amdgcn_mfma_f32_16x16x32_bf16(al[mt][kc], bh1, acc[mt][1], 0, 0, 0);
          acc[mt][1] = __builtin_amdgcn_mfma_f32_16x16x32_bf16(ah[mt][kc], bh1, acc[mt][1], 0, 0, 0);
        }
      }
      const float wn0 = wnp[0], wn1 = wnp[16];
      // acc = -(x.w); dist = wn + 2*acc
#pragma unroll
      for (int mt = 0; mt < 2; ++mt) {
#pragma unroll
        for (int reg = 0; reg < 4; ++reg) {
          const int cell = mt * 4 + reg;
          const float d0 = fmaf(2.0f, acc[mt][0][reg], wn0);
          const float d1 = fmaf(2.0f, acc[mt][1][reg], wn1);
          const float hi = fmaxf(d0, d1);
          const int ch = (d1 > d0) ? (code0 + 16) : code0;  // tie -> lower code
          bc[cell] = (hi > bv[cell]) ? ch : bc[cell];
          bv[cell] = fmaxf(bv[cell], hi);
        }
      }
      wph += (size_t)64 * DIM;
      wpl += (size_t)64 * DIM;
      wnp += 64;
      code0 += 64;
    }

    // epilogue: cross-column reduce for this g-group
    float* rv = red2;
    int* rc = (int*)(red2 + 2048);
    __syncthreads();  // protect red2 reuse across g iterations
    const int cg = wnb * 16 + l15;
#pragma unroll
    for (int mt = 0; mt < 2; ++mt)
#pragma unroll
      for (int reg = 0; reg < 4; ++reg) {
        const int tok = wm * 32 + mt * 16 + quad * 4 + reg;
        rv[tok * 32 + cg] = bv[mt * 4 + reg];
        rc[tok * 32 + cg] = bc[mt * 4 + reg];
      }
    __syncthreads();
    if (tid < 64) {
      const int s = g * 64 + tid;
      if (s < uc) {
        float V = rv[tid * 32];
        int C = rc[tid * 32];
#pragma unroll 4
        for (int j = 1; j < 32; ++j) {
          const float v = rv[tid * 32 + j];
          const int c = rc[tid * 32 + j];
          if (v > V || (v == V && c < C)) { V = v; C = c; }
        }
        p2v[(size_t)sl * NTOK + s] = V;
        p2c[(size_t)sl * NTOK + s] = C;
      }
    }
  }
}

// ---- kernel 6: fused slice-merge + gather ----
__global__ __launch_bounds__(256) void gather_kernel(const float* __restrict__ w,
    const int* __restrict__ final_idx, const float* __restrict__ p2v,
    const int* __restrict__ p2c, float* __restrict__ out) {
  const int lane = threadIdx.x & 63;
  const int n = blockIdx.x * 4 + (threadIdx.x >> 6);
  int f = final_idx[n];
  if (f & UFLAG) {
    const int s = f & 0x3FFF;
    const int sl = lane & 31;
    float v = p2v[(size_t)sl * NTOK + s];
    int c = p2c[(size_t)sl * NTOK + s];
#pragma unroll
    for (int off = 1; off < 32; off <<= 1) {
      const float ov = __shfl_xor(v, off);
      const int oc = __shfl_xor(c, off);
      if (ov > v || (ov == v && oc < c)) { v = ov; c = oc; }
    }
    f = c;  // uniform across each 32-lane half (both halves identical)
  }
  ((float4*)(out + (size_t)n * DIM))[lane] = ((const float4*)(w + (size_t)f * DIM))[lane];
}

extern "C" void kernel_launch(void* const* d_in, const int* in_sizes, int n_in,
                              void* d_out, int out_size, void* d_ws, size_t ws_size,
                              hipStream_t stream) {
  const float* x = (const float*)d_in[0];
  const float* w = (const float*)d_in[1];
  float* out = (float*)d_out;

  char* ws = (char*)d_ws;   // ~39.5 MB used
  unsigned short* x0n = (unsigned short*)(ws);             // 8388608
  unsigned short* w0 = (unsigned short*)(ws + 8388608);    // 4194304
  unsigned short* w1 = (unsigned short*)(ws + 12582912);   // 4194304
  float* wn2 = (float*)(ws + 16777216);                    // 32768
  float* wnf = (float*)(ws + 16809984);                    // 32768
  float* pv1 = (float*)(ws + 16842752);                    // 524288
  int*   pc1 = (int*)  (ws + 17367040);                    // 524288
  float* pv2 = (float*)(ws + 17891328);                    // 524288
  int* final_idx = (int*)(ws + 18415616);                  // 65536
  int* ucount = (int*)(ws + 18481152);                     // 256
  int* ulist  = (int*)(ws + 18481408);                     // 65536
  unsigned short* xgh = (unsigned short*)(ws + 18546944);  // 8388608
  unsigned short* xgl = (unsigned short*)(ws + 26935552);  // 8388608
  float* p2v = (float*)(ws + 35324160);                    // 2097152
  int*   p2c = (int*)  (ws + 37421312);                    // 2097152

  prep_kernel<<<3072, 256, 0, stream>>>(x, w, x0n, w0, w1, wn2, wnf, ucount);
  phase1_kernel<<<64 * NCBG, 256, 0, stream>>>(x0n, w0, wn2, pv1, pc1, pv2);
  reduce_kernel<<<NTOK / 256, 256, 0, stream>>>(pv1, pc1, pv2, final_idx, ucount, ulist);
  xgather_kernel<<<256, 256, 0, stream>>>(x, x0n, ucount, ulist, xgh, xgl);
  rescore_kernel<<<64 * 32, 256, 0, stream>>>(xgh, xgl, w0, w1, wnf, ucount, p2v, p2c);
  gather_kernel<<<NTOK / 4, 256, 0, stream>>>(w, final_idx, p2v, p2c, out);
}